// Round 8
// baseline (111.193 us; speedup 1.0000x reference)
//
#include <hip/hip_runtime.h>
#include <hip/hip_bf16.h>

#define NT 16384   // tokens
#define DM 4096    // d_model
#define NE 64      // experts
#define MB 32      // tokens per block
#define KSPLIT 4   // K split across the 4 waves
#define KW (DM / KSPLIT)   // 1024 k per wave
#define KSTEPS (KW / 32)   // 32 mfma K-steps per wave

typedef __attribute__((ext_vector_type(8))) short bf16x8;   // 8 bf16 = 4 VGPRs
typedef __attribute__((ext_vector_type(4))) float f32x4;

__device__ __forceinline__ unsigned short bf16_rne(float f) {
  const unsigned u = __float_as_uint(f);
  return (unsigned short)((u + 0x7FFFu + ((u >> 16) & 1u)) >> 16);
}

// hi/lo split of a float pair via packed HW cvt (RNE, same class as R7's
// validated bf16_rne). hp/lp are 2x bf16 packed (elem0 = low 16 bits).
__device__ __forceinline__ void split2(float fa, float fb, unsigned& hp, unsigned& lp) {
  union { __hip_bfloat162 h; unsigned u; } cv;
  cv.h = __float22bfloat162_rn(make_float2(fa, fb));
  hp = cv.u;
  const float ha = __uint_as_float(hp << 16);
  const float hb = __uint_as_float(hp & 0xFFFF0000u);
  cv.h = __float22bfloat162_rn(make_float2(fa - ha, fb - hb));
  lp = cv.u;
}

__device__ __forceinline__ void splitA(const float4& c0, const float4& c1,
                                       bf16x8& hi, bf16x8& lo) {
  union { unsigned u[4]; bf16x8 v; } H, L;
  split2(c0.x, c0.y, H.u[0], L.u[0]);
  split2(c0.z, c0.w, H.u[1], L.u[1]);
  split2(c1.x, c1.y, H.u[2], L.u[2]);
  split2(c1.z, c1.w, H.u[3], L.u[3]);
  hi = H.v; lo = L.v;
}

// W pre-pass (R7-validated, unchanged): fp32 -> split bf16 hi/lo in exact MFMA
// B-fragment order. id = ks*256 + nt*64 + lane;
// elem j = W[e=nt*16+(lane&15)][k=ks*32+(lane>>4)*8+j]. Idempotent.
__global__ void w_convert(const float* __restrict__ W,
                          unsigned short* __restrict__ Whi,
                          unsigned short* __restrict__ Wlo) {
  const int id   = blockIdx.x * 256 + threadIdx.x;  // 0..32767
  const int lane = id & 63;
  const int nt   = (id >> 6) & 3;
  const int ks   = id >> 8;                         // 0..127
  const float* src = W + (size_t)(nt * 16 + (lane & 15)) * DM + ks * 32 + (lane >> 4) * 8;
  unsigned short h[8], l[8];
#pragma unroll
  for (int j = 0; j < 8; ++j) {
    const float f = src[j];
    h[j] = bf16_rne(f);
    l[j] = bf16_rne(f - __uint_as_float((unsigned)h[j] << 16));
  }
  uint4 ph, pl;
  ph.x = h[0] | ((unsigned)h[1] << 16); ph.y = h[2] | ((unsigned)h[3] << 16);
  ph.z = h[4] | ((unsigned)h[5] << 16); ph.w = h[6] | ((unsigned)h[7] << 16);
  pl.x = l[0] | ((unsigned)l[1] << 16); pl.y = l[2] | ((unsigned)l[3] << 16);
  pl.z = l[4] | ((unsigned)l[5] << 16); pl.w = l[6] | ((unsigned)l[7] << 16);
  *(uint4*)(Whi + (size_t)id * 8) = ph;
  *(uint4*)(Wlo + (size_t)id * 8) = pl;
}

// Main: block = 256 thr = 4 waves; wave w = 32 block-tokens x 64 experts,
// x K-slice [w*1024,(w+1)*1024). A-frags per-lane direct from x (row =
// mt*16+(l&15), k = (l>>4)*8+j), packed-cvt split to bf16 hi/lo in regs.
// 4-pass mfma (ll+lh+hl+hh) == fp32-accurate dot product (R7-validated).
// A and B both 1-kstep register-prefetched; no LDS/barriers in K loop.
__launch_bounds__(256, 3)
__global__ void moe_mfma(const float* __restrict__ x,
                         const unsigned short* __restrict__ Whi,
                         const unsigned short* __restrict__ Wlo,
                         float* __restrict__ out,
                         float* __restrict__ bsum) {
  __shared__ float slab[KSPLIT][8][66];   // [k-wave][tok-in-slice][expert]
  __shared__ float esums[4][NE];

  const int tid  = threadIdx.x;
  const int lane = tid & 63;
  const int wv   = tid >> 6;
  const int wvu  = __builtin_amdgcn_readfirstlane(wv);
  const int blk  = blockIdx.x;

  const float* ap0 = x + (size_t)(blk * MB + (lane & 15)) * DM + wv * KW + (lane >> 4) * 8;
  const float* ap1 = ap0 + (size_t)16 * DM;
  const unsigned short* bh_p = Whi + (size_t)(wv * KSTEPS) * 2048 + lane * 8;
  const unsigned short* bl_p = Wlo + (size_t)(wv * KSTEPS) * 2048 + lane * 8;

  f32x4 acc[2][4];
#pragma unroll
  for (int mt = 0; mt < 2; ++mt)
#pragma unroll
    for (int nt = 0; nt < 4; ++nt) acc[mt][nt] = (f32x4){0.f, 0.f, 0.f, 0.f};

  // current A (fp32) and B (bf16 frags)
  float4 a00 = *(const float4*)(ap0);
  float4 a01 = *(const float4*)(ap0 + 4);
  float4 a10 = *(const float4*)(ap1);
  float4 a11 = *(const float4*)(ap1 + 4);
  bf16x8 bh[4], bl[4];
#pragma unroll
  for (int nt = 0; nt < 4; ++nt) {
    bh[nt] = *(const bf16x8*)(bh_p + nt * 512);
    bl[nt] = *(const bf16x8*)(bl_p + nt * 512);
  }

#pragma unroll 2
  for (int i = 0; i < KSTEPS; ++i) {
    // prefetch kstep i+1 (A from HBM, B from L2) while computing kstep i
    float4 p00, p01, p10, p11;
    bf16x8 nh[4], nl[4];
    if (i + 1 < KSTEPS) {
      const int o = (i + 1) * 32;
      p00 = *(const float4*)(ap0 + o);
      p01 = *(const float4*)(ap0 + o + 4);
      p10 = *(const float4*)(ap1 + o);
      p11 = *(const float4*)(ap1 + o + 4);
      const size_t fb = (size_t)(i + 1) * 2048;
#pragma unroll
      for (int nt = 0; nt < 4; ++nt) {
        nh[nt] = *(const bf16x8*)(bh_p + fb + nt * 512);
        nl[nt] = *(const bf16x8*)(bl_p + fb + nt * 512);
      }
    }

    // split-convert A in registers (packed HW cvt)
    bf16x8 ah0, al0, ah1, al1;
    splitA(a00, a01, ah0, al0);
    splitA(a10, a11, ah1, al1);

    // 4-pass mfma: ll + lh + hl + hh (bf16 products exact in fp32)
#pragma unroll
    for (int nt = 0; nt < 4; ++nt) {
      acc[0][nt] = __builtin_amdgcn_mfma_f32_16x16x32_bf16(al0, bl[nt], acc[0][nt], 0, 0, 0);
      acc[0][nt] = __builtin_amdgcn_mfma_f32_16x16x32_bf16(al0, bh[nt], acc[0][nt], 0, 0, 0);
      acc[0][nt] = __builtin_amdgcn_mfma_f32_16x16x32_bf16(ah0, bl[nt], acc[0][nt], 0, 0, 0);
      acc[0][nt] = __builtin_amdgcn_mfma_f32_16x16x32_bf16(ah0, bh[nt], acc[0][nt], 0, 0, 0);
      acc[1][nt] = __builtin_amdgcn_mfma_f32_16x16x32_bf16(al1, bl[nt], acc[1][nt], 0, 0, 0);
      acc[1][nt] = __builtin_amdgcn_mfma_f32_16x16x32_bf16(al1, bh[nt], acc[1][nt], 0, 0, 0);
      acc[1][nt] = __builtin_amdgcn_mfma_f32_16x16x32_bf16(ah1, bl[nt], acc[1][nt], 0, 0, 0);
      acc[1][nt] = __builtin_amdgcn_mfma_f32_16x16x32_bf16(ah1, bh[nt], acc[1][nt], 0, 0, 0);
    }

    if (i + 1 < KSTEPS) {
      a00 = p00; a01 = p01; a10 = p10; a11 = p11;
#pragma unroll
      for (int nt = 0; nt < 4; ++nt) { bh[nt] = nh[nt]; bl[nt] = nl[nt]; }
    }
  }

  // Deterministic k-split combine. D layout (m89): row=(l>>4)*4+r, col=l&15;
  // token = mt*16 + (l>>4)*4 + r. Round s covers tokens [8s, 8s+8).
  float lg[8];
#pragma unroll
  for (int s = 0; s < 4; ++s) {
    const int mt = s >> 1;
    const int g  = 2 * (s & 1);
    const int q  = lane >> 4;
    if (q == g || q == g + 1) {
#pragma unroll
      for (int nt = 0; nt < 4; ++nt)
#pragma unroll
        for (int r = 0; r < 4; ++r)
          slab[wv][(q - g) * 4 + r][nt * 16 + (lane & 15)] = acc[mt][nt][r];
    }
    __syncthreads();
    if (wvu == s) {
#pragma unroll
      for (int t = 0; t < 8; ++t) {
        float v = 0.f;
#pragma unroll
        for (int w = 0; w < KSPLIT; ++w) v += slab[w][t][lane];
        lg[t] = v;
      }
    }
    __syncthreads();
  }

  // Epilogue (validated): wave wvu owns tokens blk*32 + wvu*8 + ti; lane <-> expert.
  float esum = 0.f;
#pragma unroll
  for (int ti = 0; ti < 8; ++ti) {
    const float lgv = lg[ti];
    float m = lgv;
#pragma unroll
    for (int off = 32; off; off >>= 1) m = fmaxf(m, __shfl_xor(m, off, 64));
    const float p = __expf(lgv - m);
    float Z = p;
#pragma unroll
    for (int off = 32; off; off >>= 1) Z += __shfl_xor(Z, off, 64);
    const float s = p / Z;
    esum += s;

    // top-1 (value desc, index asc — matches lax.top_k tie-break)
    float v1 = s; int i1 = lane;
#pragma unroll
    for (int off = 32; off; off >>= 1) {
      const float ov = __shfl_xor(v1, off, 64);
      const int   oi = __shfl_xor(i1, off, 64);
      if (ov > v1 || (ov == v1 && oi < i1)) { v1 = ov; i1 = oi; }
    }
    // top-2: mask winner (scores >= 0, so -1 acts as -inf)
    float sv = (lane == i1) ? -1.f : s;
    float v2 = sv; int i2 = lane;
#pragma unroll
    for (int off = 32; off; off >>= 1) {
      const float ov = __shfl_xor(v2, off, 64);
      const int   oi = __shfl_xor(i2, off, 64);
      if (ov > v2 || (ov == v2 && oi < i2)) { v2 = ov; i2 = oi; }
    }

    if (lane == 0) {
      const int gt = blk * MB + wvu * 8 + ti;
      const float inv = 1.f / (v1 + v2);
      out[2 * gt]              = v1 * inv;
      out[2 * gt + 1]          = v2 * inv;
      out[2 * NT + 2 * gt]     = (float)i1;
      out[2 * NT + 2 * gt + 1] = (float)i2;
    }
  }

  // per-block expert score sums (deterministic tree reduce, no atomics)
  esums[wvu][lane] = esum;
  __syncthreads();
  if (wvu == 0) {
    float tot = esums[0][lane] + esums[1][lane] + esums[2][lane] + esums[3][lane];
    bsum[blk * NE + lane] = tot;
  }
}

// Reduce NT/MB per-block expert sums -> load balancing loss
__global__ void moe_gate_loss(const float* __restrict__ bsum,
                              float* __restrict__ out) {
  __shared__ float red[4][64];
  const int e = threadIdx.x & 63;
  const int g = threadIdx.x >> 6;
  float s = 0.f;
  for (int b = g; b < NT / MB; b += 4) s += bsum[b * 64 + e];
  red[g][e] = s;
  __syncthreads();
  if (threadIdx.x < 64) {
    const float tot = red[0][e] + red[1][e] + red[2][e] + red[3][e];
    const float p = tot * (1.f / (float)NT);
    float term = p * logf(p + 1e-8f);
#pragma unroll
    for (int off = 32; off; off >>= 1) term += __shfl_xor(term, off, 64);
    if (e == 0) out[4 * NT] = term;  // out[65536]
  }
}

extern "C" void kernel_launch(void* const* d_in, const int* in_sizes, int n_in,
                              void* d_out, int out_size, void* d_ws, size_t ws_size,
                              hipStream_t stream) {
  const float* x = (const float*)d_in[0];   // [16384, 4096]
  const float* W = (const float*)d_in[1];   // [64, 4096]
  float* out = (float*)d_out;               // scores[32768] | idx[32768] | loss[1]

  unsigned short* Whi = (unsigned short*)d_ws;        // 512 KiB
  unsigned short* Wlo = Whi + (size_t)NE * DM;        // 512 KiB
  float* bsum = (float*)(Wlo + (size_t)NE * DM);      // [512][64]

  hipLaunchKernelGGL(w_convert, dim3(128), dim3(256), 0, stream, W, Whi, Wlo);
  hipLaunchKernelGGL(moe_mfma, dim3(NT / MB), dim3(256), 0, stream, x, Whi, Wlo, out, bsum);
  hipLaunchKernelGGL(moe_gate_loss, dim3(1), dim3(256), 0, stream, bsum, out);
}

// Round 9
// 106.045 us; speedup vs baseline: 1.0485x; 1.0485x over previous
//
#include <hip/hip_runtime.h>
#include <hip/hip_bf16.h>

#define NT 16384   // tokens
#define DM 4096    // d_model
#define NE 64      // experts
#define MB 64      // tokens per block
#define BK 128     // K per staged tile
#define NST (DM / BK)   // 32 stages, 4 ksteps each
#define LROW 132   // padded LDS row stride (floats): bank-balanced for write & read

typedef __attribute__((ext_vector_type(8))) short bf16x8;   // 8 bf16 = 4 VGPRs
typedef __attribute__((ext_vector_type(4))) float f32x4;

__device__ __forceinline__ unsigned short bf16_rne(float f) {
  const unsigned u = __float_as_uint(f);
  return (unsigned short)((u + 0x7FFFu + ((u >> 16) & 1u)) >> 16);
}

// hi/lo split of a float pair via packed HW cvt (RNE; R7/R8-validated class)
__device__ __forceinline__ void split2(float fa, float fb, unsigned& hp, unsigned& lp) {
  union { __hip_bfloat162 h; unsigned u; } cv;
  cv.h = __float22bfloat162_rn(make_float2(fa, fb));
  hp = cv.u;
  const float ha = __uint_as_float(hp << 16);
  const float hb = __uint_as_float(hp & 0xFFFF0000u);
  cv.h = __float22bfloat162_rn(make_float2(fa - ha, fb - hb));
  lp = cv.u;
}

__device__ __forceinline__ void splitA(const float4& c0, const float4& c1,
                                       bf16x8& hi, bf16x8& lo) {
  union { unsigned u[4]; bf16x8 v; } H, L;
  split2(c0.x, c0.y, H.u[0], L.u[0]);
  split2(c0.z, c0.w, H.u[1], L.u[1]);
  split2(c1.x, c1.y, H.u[2], L.u[2]);
  split2(c1.z, c1.w, H.u[3], L.u[3]);
  hi = H.v; lo = L.v;
}

// W pre-pass (R7-validated, unchanged): fp32 -> split bf16 hi/lo in exact MFMA
// B-fragment order. id = ks*256 + nt*64 + lane;
// elem j = W[e=nt*16+(lane&15)][k=ks*32+(lane>>4)*8+j]. Idempotent.
__global__ void w_convert(const float* __restrict__ W,
                          unsigned short* __restrict__ Whi,
                          unsigned short* __restrict__ Wlo) {
  const int id   = blockIdx.x * 256 + threadIdx.x;  // 0..32767
  const int lane = id & 63;
  const int nt   = (id >> 6) & 3;
  const int ks   = id >> 8;                         // 0..127
  const float* src = W + (size_t)(nt * 16 + (lane & 15)) * DM + ks * 32 + (lane >> 4) * 8;
  unsigned short h[8], l[8];
#pragma unroll
  for (int j = 0; j < 8; ++j) {
    const float f = src[j];
    h[j] = bf16_rne(f);
    l[j] = bf16_rne(f - __uint_as_float((unsigned)h[j] << 16));
  }
  uint4 ph, pl;
  ph.x = h[0] | ((unsigned)h[1] << 16); ph.y = h[2] | ((unsigned)h[3] << 16);
  ph.z = h[4] | ((unsigned)h[5] << 16); ph.w = h[6] | ((unsigned)h[7] << 16);
  pl.x = l[0] | ((unsigned)l[1] << 16); pl.y = l[2] | ((unsigned)l[3] << 16);
  pl.z = l[4] | ((unsigned)l[5] << 16); pl.w = l[6] | ((unsigned)l[7] << 16);
  *(uint4*)(Whi + (size_t)id * 8) = ph;
  *(uint4*)(Wlo + (size_t)id * 8) = pl;
}

// Main fused kernel. Block = 512 thr = 8 waves; wave (tg=wv>>1, eg=wv&1) owns
// tokens [16tg,16tg+16) x experts [32eg,32eg+32), full K. x staged per 128-k
// stage into padded LDS [64][132] with contiguous 512B/row global bursts
// (reg-staged, issued one full stage ahead). A-frags read ds_read_b128 from
// LDS (bank-balanced), packed-cvt split to bf16 hi/lo; B frags (precomputed
// order) 1-deep register prefetch from L2/L1. 4-pass mfma == fp32-accurate
// dot product (validated). Epilogue fused (validated verbatim).
__launch_bounds__(512, 2)
__global__ void moe_mfma(const float* __restrict__ x,
                         const unsigned short* __restrict__ Whi,
                         const unsigned short* __restrict__ Wlo,
                         float* __restrict__ out,
                         float* __restrict__ bsum) {
  __shared__ float xs[2][MB][LROW];   // 67.6 KiB
  __shared__ float esums[8][NE];
  float* lg = &xs[0][0][0];           // reused as [64][65] after the K loop

  const int tid  = threadIdx.x;
  const int lane = tid & 63;
  const int wv   = tid >> 6;
  const int wvu  = __builtin_amdgcn_readfirstlane(wv);
  const int tg   = wvu >> 1;          // token group 0..3
  const int eg   = wvu & 1;           // expert half 0..1
  const int blk  = blockIdx.x;
  const int tok0 = blk * MB;

  // ---- staging role: thread t -> row t>>3, float cols (t&7)*4 + j*32 ----
  const int srow = tid >> 3;
  const int scol = (tid & 7) * 4;
  const float* xrow = x + (size_t)(tok0 + srow) * DM + scol;

  float4 g0, g1, g2, g3;
#define LOADSTAGE(s) {                                        \
    const float* p = xrow + (size_t)(s) * BK;                 \
    g0 = *(const float4*)(p);                                 \
    g1 = *(const float4*)(p + 32);                            \
    g2 = *(const float4*)(p + 64);                            \
    g3 = *(const float4*)(p + 96); }
#define WRITESTAGE(b) {                                       \
    float* q = &xs[b][srow][scol];                            \
    *(float4*)(q)      = g0;                                  \
    *(float4*)(q + 32) = g1;                                  \
    *(float4*)(q + 64) = g2;                                  \
    *(float4*)(q + 96) = g3; }

  // ---- B pointers (frag order: (gk*4 + nt)*512 + lane*8; nt = eg*2 + ntl) ----
  const unsigned short* bhp = Whi + (size_t)(eg * 2) * 512 + lane * 8;
  const unsigned short* blp = Wlo + (size_t)(eg * 2) * 512 + lane * 8;
  bf16x8 Bh0[2], Bl0[2], Bh1[2], Bl1[2];
#define LOADB(BH, BL, gk) {                                   \
    const size_t o = (size_t)(gk) * 2048;                     \
    BH[0] = *(const bf16x8*)(bhp + o);                        \
    BH[1] = *(const bf16x8*)(bhp + o + 512);                  \
    BL[0] = *(const bf16x8*)(blp + o);                        \
    BL[1] = *(const bf16x8*)(blp + o + 512); }

  // ---- A-frag read base: row = 16tg + (l&15), cols (l>>4)*8 + kk*32 ----
  const int arow = tg * 16 + (lane & 15);
  const int acol = (lane >> 4) * 8;

  f32x4 acc0 = (f32x4){0.f, 0.f, 0.f, 0.f};
  f32x4 acc1 = (f32x4){0.f, 0.f, 0.f, 0.f};

#define STEP(b, kk, BH, BL) {                                                          \
    const float* ap = &xs[b][arow][acol + (kk) * 32];                                  \
    const float4 f0 = *(const float4*)(ap);                                            \
    const float4 f1 = *(const float4*)(ap + 4);                                        \
    bf16x8 ah, al;                                                                     \
    splitA(f0, f1, ah, al);                                                            \
    acc0 = __builtin_amdgcn_mfma_f32_16x16x32_bf16(al, BL[0], acc0, 0, 0, 0);          \
    acc0 = __builtin_amdgcn_mfma_f32_16x16x32_bf16(al, BH[0], acc0, 0, 0, 0);          \
    acc0 = __builtin_amdgcn_mfma_f32_16x16x32_bf16(ah, BL[0], acc0, 0, 0, 0);          \
    acc0 = __builtin_amdgcn_mfma_f32_16x16x32_bf16(ah, BH[0], acc0, 0, 0, 0);          \
    acc1 = __builtin_amdgcn_mfma_f32_16x16x32_bf16(al, BL[1], acc1, 0, 0, 0);          \
    acc1 = __builtin_amdgcn_mfma_f32_16x16x32_bf16(al, BH[1], acc1, 0, 0, 0);          \
    acc1 = __builtin_amdgcn_mfma_f32_16x16x32_bf16(ah, BL[1], acc1, 0, 0, 0);          \
    acc1 = __builtin_amdgcn_mfma_f32_16x16x32_bf16(ah, BH[1], acc1, 0, 0, 0); }

  // prologue
  LOADSTAGE(0);
  LOADB(Bh0, Bl0, 0);
  WRITESTAGE(0);
  __syncthreads();

  for (int s = 0; s < NST; ++s) {
    const int b = s & 1;
    if (s + 1 < NST) LOADSTAGE(s + 1);   // issue next tile early (hides HBM lat.)
    const int g4 = s * 4;
    const int n1 = g4 + 1, n2 = g4 + 2, n3 = g4 + 3;
    const int n4 = (g4 + 4 < 128) ? g4 + 4 : 127;  // clamped (unused garbage ok)
    LOADB(Bh1, Bl1, n1); STEP(b, 0, Bh0, Bl0);
    LOADB(Bh0, Bl0, n2); STEP(b, 1, Bh1, Bl1);
    LOADB(Bh1, Bl1, n3); STEP(b, 2, Bh0, Bl0);
    LOADB(Bh0, Bl0, n4); STEP(b, 3, Bh1, Bl1);
    if (s + 1 < NST) WRITESTAGE((s + 1) & 1);
    __syncthreads();
  }

  // acc -> lg[tok][exp] (lg reuses xs[0]; last compute read xs[1]; barrier passed)
  // D layout (m89, validated): token = 16tg + (l>>4)*4 + r, expert = 32eg + nt*16 + (l&15)
#pragma unroll
  for (int r = 0; r < 4; ++r) {
    const int t = tg * 16 + (lane >> 4) * 4 + r;
    lg[t * 65 + eg * 32 + (lane & 15)]      = acc0[r];
    lg[t * 65 + eg * 32 + 16 + (lane & 15)] = acc1[r];
  }
  __syncthreads();

  // Epilogue (validated verbatim): wave wvu owns tokens blk*64 + wvu*8 + ti.
  float esum = 0.f;
#pragma unroll
  for (int ti = 0; ti < 8; ++ti) {
    const int t = wvu * 8 + ti;
    const float lgv = lg[t * 65 + lane];

    float m = lgv;
#pragma unroll
    for (int off = 32; off; off >>= 1) m = fmaxf(m, __shfl_xor(m, off, 64));
    const float p = __expf(lgv - m);
    float Z = p;
#pragma unroll
    for (int off = 32; off; off >>= 1) Z += __shfl_xor(Z, off, 64);
    const float s = p / Z;
    esum += s;

    // top-1 (value desc, index asc — matches lax.top_k tie-break)
    float v1 = s; int i1 = lane;
#pragma unroll
    for (int off = 32; off; off >>= 1) {
      const float ov = __shfl_xor(v1, off, 64);
      const int   oi = __shfl_xor(i1, off, 64);
      if (ov > v1 || (ov == v1 && oi < i1)) { v1 = ov; i1 = oi; }
    }
    // top-2: mask winner (scores >= 0, so -1 acts as -inf)
    float sv = (lane == i1) ? -1.f : s;
    float v2 = sv; int i2 = lane;
#pragma unroll
    for (int off = 32; off; off >>= 1) {
      const float ov = __shfl_xor(v2, off, 64);
      const int   oi = __shfl_xor(i2, off, 64);
      if (ov > v2 || (ov == v2 && oi < i2)) { v2 = ov; i2 = oi; }
    }

    if (lane == 0) {
      const int gt = tok0 + t;
      const float inv = 1.f / (v1 + v2);
      out[2 * gt]              = v1 * inv;
      out[2 * gt + 1]          = v2 * inv;
      out[2 * NT + 2 * gt]     = (float)i1;
      out[2 * NT + 2 * gt + 1] = (float)i2;
    }
  }

  // per-block expert score sums (deterministic tree reduce, no atomics)
  esums[wvu][lane] = esum;
  __syncthreads();
  if (wvu == 0) {
    float tot = 0.f;
#pragma unroll
    for (int w = 0; w < 8; ++w) tot += esums[w][lane];
    bsum[blk * NE + lane] = tot;
  }
}

// Reduce 256 per-block expert sums -> load balancing loss
__global__ void moe_gate_loss(const float* __restrict__ bsum,
                              float* __restrict__ out) {
  __shared__ float red[4][64];
  const int e = threadIdx.x & 63;
  const int g = threadIdx.x >> 6;
  float s = 0.f;
  for (int b = g; b < NT / MB; b += 4) s += bsum[b * 64 + e];
  red[g][e] = s;
  __syncthreads();
  if (threadIdx.x < 64) {
    const float tot = red[0][e] + red[1][e] + red[2][e] + red[3][e];
    const float p = tot * (1.f / (float)NT);
    float term = p * logf(p + 1e-8f);
#pragma unroll
    for (int off = 32; off; off >>= 1) term += __shfl_xor(term, off, 64);
    if (e == 0) out[4 * NT] = term;  // out[65536]
  }
}

extern "C" void kernel_launch(void* const* d_in, const int* in_sizes, int n_in,
                              void* d_out, int out_size, void* d_ws, size_t ws_size,
                              hipStream_t stream) {
  const float* x = (const float*)d_in[0];   // [16384, 4096]
  const float* W = (const float*)d_in[1];   // [64, 4096]
  float* out = (float*)d_out;               // scores[32768] | idx[32768] | loss[1]

  unsigned short* Whi = (unsigned short*)d_ws;        // 512 KiB
  unsigned short* Wlo = Whi + (size_t)NE * DM;        // 512 KiB
  float* bsum = (float*)(Wlo + (size_t)NE * DM);      // [256][64]

  hipLaunchKernelGGL(w_convert, dim3(128), dim3(256), 0, stream, W, Whi, Wlo);
  hipLaunchKernelGGL(moe_mfma, dim3(NT / MB), dim3(512), 0, stream, x, Whi, Wlo, out, bsum);
  hipLaunchKernelGGL(moe_gate_loss, dim3(1), dim3(256), 0, stream, bsum, out);
}